// Round 4
// baseline (433.800 us; speedup 1.0000x reference)
//
#include <hip/hip_runtime.h>
#include <hip/hip_cooperative_groups.h>

namespace cg = cooperative_groups;

constexpr int Bn = 8;
constexpr int Ln = 4096;
constexpr int Dn = 768;
constexpr int D4 = Dn / 4;                 // 192 float4 columns

typedef float vfloat4 __attribute__((ext_vector_type(4)));

// ------------------------- cooperative single-kernel ------------------------
constexpr int TPB    = 192;                // 3 waves/block, thread t = float4 col
constexpr int BLOCKS = 2048;               // 8 blocks/CU, 24 waves/CU co-resident
constexpr int BPB    = BLOCKS / Bn;        // 256 blocks per batch
constexpr int RPB    = Ln / BPB;           // 16 rows per block

// P1: per-block colsum partials (same access pattern as proven K1) ->
//     4 device-scope atomicAdds into zeroed colsum[b][:] (order-nondeterminism
//     is invisible: coef ~1e-11, |coef*x| << ulp(alpha)).
// grid.sync (ONE sync; no low-occupancy serial phase anywhere).
// P2: block-local ssq -> scale (butterfly + 3-wave LDS combine).
// P3: wave-per-row dot + NT-store epilogue (same pattern as proven K3).
__global__ __launch_bounds__(TPB, 3)
void k_all(const float4* __restrict__ x, const float* __restrict__ alpha,
           vfloat4* __restrict__ out, float* __restrict__ colsum) {
    cg::grid_group grid = cg::this_grid();
    const int t    = threadIdx.x;          // 0..191
    const int b    = blockIdx.x / BPB;
    const int sub  = blockIdx.x % BPB;
    const int row0 = b * Ln + sub * RPB;   // first global row of this block

    // ---------------- P1: 16-row partial column sums + atomic fold ----------
    const float4* p = x + (size_t)row0 * D4 + t;
    float4 s = {0.f, 0.f, 0.f, 0.f};
    #pragma unroll 8
    for (int l = 0; l < RPB; ++l) {
        float4 v = p[(size_t)l * D4];
        s.x += v.x; s.y += v.y; s.z += v.z; s.w += v.w;
    }
    float* cb = colsum + b * Dn + t * 4;
    atomicAdd(cb + 0, s.x);
    atomicAdd(cb + 1, s.y);
    atomicAdd(cb + 2, s.z);
    atomicAdd(cb + 3, s.w);

    grid.sync();

    // ---------------- P2: block-local scale = ||colsum_b||^2/(L^4 D^2) ------
    const float4* cs = (const float4*)(colsum + b * Dn);
    float4 cm = cs[t];
    float ssq = cm.x * cm.x + cm.y * cm.y + cm.z * cm.z + cm.w * cm.w;
    #pragma unroll
    for (int off = 1; off < 64; off <<= 1) ssq += __shfl_xor(ssq, off);
    __shared__ float wsum[3];
    const int wave = t >> 6, lane = t & 63;
    if (lane == 0) wsum[wave] = ssq;
    __syncthreads();
    const float f1 = 1.0f / ((float)Ln * (float)Dn);
    const float scale = (wsum[0] + wsum[1] + wsum[2]) * f1 * f1
                        / ((float)Ln * (float)Ln);

    // ---------------- P3: wave-per-row dot + epilogue (rows of this block) --
    float4 c0 = cs[lane], c1 = cs[lane + 64], c2 = cs[lane + 128];
    for (int r = wave; r < RPB; r += 3) {
        const int row = row0 + r;
        const float4* xr = x + (size_t)row * D4;
        float4 x0 = xr[lane], x1 = xr[lane + 64], x2 = xr[lane + 128];
        float acc = x0.x * c0.x + x0.y * c0.y + x0.z * c0.z + x0.w * c0.w
                  + x1.x * c1.x + x1.y * c1.y + x1.z * c1.z + x1.w * c1.w
                  + x2.x * c2.x + x2.y * c2.y + x2.z * c2.z + x2.w * c2.w;
        #pragma unroll
        for (int off = 1; off < 64; off <<= 1) acc += __shfl_xor(acc, off);
        const float coef = acc * scale;
        const float a = alpha[row & (Ln - 1)];
        vfloat4* orow = (vfloat4*)out + (size_t)row * D4;
        vfloat4 o0 = {a + coef * x0.x, a + coef * x0.y, a + coef * x0.z, a + coef * x0.w};
        vfloat4 o1 = {a + coef * x1.x, a + coef * x1.y, a + coef * x1.z, a + coef * x1.w};
        vfloat4 o2 = {a + coef * x2.x, a + coef * x2.y, a + coef * x2.z, a + coef * x2.w};
        __builtin_nontemporal_store(o0, &orow[lane]);
        __builtin_nontemporal_store(o1, &orow[lane + 64]);
        __builtin_nontemporal_store(o2, &orow[lane + 128]);
    }
}

// ------------------- fallback: proven 3-kernel path (round 3) ---------------
constexpr int CPB = 128;
constexpr int CHUNKS_TOT = Bn * CPB;
constexpr int RPC = Ln / CPB;

__global__ __launch_bounds__(192)
void k_colsum_part(const float4* __restrict__ x, float4* __restrict__ part) {
    const int ch = blockIdx.x;
    const int t  = threadIdx.x;
    const float4* p = x + (size_t)ch * RPC * D4 + t;
    float4 s = {0.f, 0.f, 0.f, 0.f};
    #pragma unroll 8
    for (int l = 0; l < RPC; ++l) {
        float4 v = p[(size_t)l * D4];
        s.x += v.x; s.y += v.y; s.z += v.z; s.w += v.w;
    }
    part[(size_t)ch * D4 + t] = s;
}

__global__ __launch_bounds__(64)
void k_colsum_fold(const float* __restrict__ part, float* __restrict__ colsum) {
    const int b    = blockIdx.x / 12;
    const int sl   = blockIdx.x % 12;
    const int lane = threadIdx.x;
    const float* pb = part + (size_t)b * CPB * Dn + sl * 64 + lane;
    float s = 0.f;
    #pragma unroll 8
    for (int c = 0; c < CPB; ++c) s += pb[(size_t)c * Dn];
    colsum[b * Dn + sl * 64 + lane] = s;
}

__global__ __launch_bounds__(256)
void k_fused(const float4* __restrict__ x, const float4* __restrict__ colsum,
             const float* __restrict__ alpha, vfloat4* __restrict__ out) {
    const int wave = threadIdx.x >> 6;
    const int lane = threadIdx.x & 63;
    const int row  = blockIdx.x * 4 + wave;
    const int b    = row >> 12;
    const int l    = row & (Ln - 1);

    const float4* cs = colsum + (size_t)b * D4;
    float4 c0 = cs[lane], c1 = cs[lane + 64], c2 = cs[lane + 128];
    float ssq = c0.x * c0.x + c0.y * c0.y + c0.z * c0.z + c0.w * c0.w
              + c1.x * c1.x + c1.y * c1.y + c1.z * c1.z + c1.w * c1.w
              + c2.x * c2.x + c2.y * c2.y + c2.z * c2.z + c2.w * c2.w;
    #pragma unroll
    for (int off = 1; off < 64; off <<= 1) ssq += __shfl_xor(ssq, off);

    const float4* xr = x + (size_t)row * D4;
    float4 x0 = xr[lane], x1 = xr[lane + 64], x2 = xr[lane + 128];
    float acc = x0.x * c0.x + x0.y * c0.y + x0.z * c0.z + x0.w * c0.w
              + x1.x * c1.x + x1.y * c1.y + x1.z * c1.z + x1.w * c1.w
              + x2.x * c2.x + x2.y * c2.y + x2.z * c2.z + x2.w * c2.w;
    #pragma unroll
    for (int off = 1; off < 64; off <<= 1) acc += __shfl_xor(acc, off);

    const float f1 = 1.0f / ((float)Ln * (float)Dn);
    const float k  = ssq * f1 * f1 / ((float)Ln * (float)Ln);
    const float coef = acc * k;

    const float a = alpha[l];
    vfloat4* orow = out + (size_t)row * D4;
    vfloat4 o0 = {a + coef * x0.x, a + coef * x0.y, a + coef * x0.z, a + coef * x0.w};
    vfloat4 o1 = {a + coef * x1.x, a + coef * x1.y, a + coef * x1.z, a + coef * x1.w};
    vfloat4 o2 = {a + coef * x2.x, a + coef * x2.y, a + coef * x2.z, a + coef * x2.w};
    __builtin_nontemporal_store(o0, &orow[lane]);
    __builtin_nontemporal_store(o1, &orow[lane + 64]);
    __builtin_nontemporal_store(o2, &orow[lane + 128]);
}

// ---------------------------------------------------------------------------
extern "C" void kernel_launch(void* const* d_in, const int* in_sizes, int n_in,
                              void* d_out, int out_size, void* d_ws, size_t ws_size,
                              hipStream_t stream) {
    const float* x     = (const float*)d_in[0];   // [B, L, D]
    const float* alpha = (const float*)d_in[1];   // [L, 1]
    float* out = (float*)d_out;                   // [B, L, D]

    // ws layout: colsum[8*768] (24 KB) | part[1024*768] (3 MB, fallback only)
    float* colsum = (float*)d_ws;
    float* part   = colsum + (size_t)Bn * Dn;

    // zero colsum for the atomic fold (graph-capturable async memset)
    hipMemsetAsync(colsum, 0, (size_t)Bn * Dn * sizeof(float), stream);

    const float4* x4 = (const float4*)x;
    vfloat4* out4 = (vfloat4*)out;
    void* args[] = {(void*)&x4, (void*)&alpha, (void*)&out4, (void*)&colsum};
    hipError_t err = hipLaunchCooperativeKernel(
        reinterpret_cast<const void*>(k_all), dim3(BLOCKS), dim3(TPB),
        args, 0u, stream);

    if (err != hipSuccess) {   // co-residency rejected -> proven 3-kernel path
        k_colsum_part<<<CHUNKS_TOT, 192, 0, stream>>>(x4, (float4*)part);
        k_colsum_fold<<<Bn * 12, 64, 0, stream>>>(part, colsum);
        k_fused<<<(Bn * Ln) / 4, 256, 0, stream>>>(x4, (const float4*)colsum,
                                                   alpha, out4);
    }
}

// Round 5
// 198.298 us; speedup vs baseline: 2.1876x; 2.1876x over previous
//
#include <hip/hip_runtime.h>

constexpr int Bn = 8;
constexpr int Ln = 4096;
constexpr int Dn = 768;
constexpr int D4 = Dn / 4;               // 192 float4 columns
constexpr int CPB = 128;                 // chunks per batch
constexpr int CHUNKS_TOT = Bn * CPB;     // 1024 blocks in K1
constexpr int RPC = Ln / CPB;            // 32 rows per chunk

typedef float vfloat4 __attribute__((ext_vector_type(4)));  // clang-native vec4

// ---------------------------------------------------------------------------
// K1: partial column sums (unchanged, proven). grid = 1024 x 192.
// Thread t owns float4-column t; 32 rows per chunk; perfect 1KB/wave coalescing.
// part[ch][d] = sum over the chunk's 32 rows.
// ---------------------------------------------------------------------------
__global__ __launch_bounds__(192)
void k_colsum_part(const float4* __restrict__ x, float4* __restrict__ part) {
    const int ch = blockIdx.x;
    const int t  = threadIdx.x;          // 0..191
    const float4* p = x + (size_t)ch * RPC * D4 + t;
    float4 s = {0.f, 0.f, 0.f, 0.f};
    #pragma unroll 8
    for (int l = 0; l < RPC; ++l) {
        float4 v = p[(size_t)l * D4];
        s.x += v.x; s.y += v.y; s.z += v.z; s.w += v.w;
    }
    part[(size_t)ch * D4 + t] = s;
}

// ---------------------------------------------------------------------------
// K2: one block per batch, 768 threads (12 waves). Thread d folds the 128
// partials of column d (coalesced: consecutive threads -> consecutive addrs),
// block-reduces ssq = ||colsum||^2, and writes PREMULTIPLIED
//   m[b,d] = colsum[b,d] * ssq / (L^4 D^2)
// so K3 needs only ONE butterfly per row (coef = x_row . m directly).
// 3 MB total read across 8 blocks, ~3-5 us, off the critical-BW path.
// ---------------------------------------------------------------------------
__global__ __launch_bounds__(768)
void k_scale_m(const float* __restrict__ part, float* __restrict__ m) {
    const int b = blockIdx.x;
    const int d = threadIdx.x;           // 0..767
    const float* pb = part + (size_t)b * CPB * Dn + d;
    float s = 0.f;
    #pragma unroll 8
    for (int c = 0; c < CPB; ++c) s += pb[(size_t)c * Dn];

    float ssq = s * s;
    #pragma unroll
    for (int off = 1; off < 64; off <<= 1) ssq += __shfl_xor(ssq, off);
    __shared__ float wsum[12];
    const int wave = d >> 6, lane = d & 63;
    if (lane == 0) wsum[wave] = ssq;
    __syncthreads();
    float ss = 0.f;
    #pragma unroll
    for (int i = 0; i < 12; ++i) ss += wsum[i];

    const float f1 = 1.0f / ((float)Ln * (float)Dn);              // 1/(L*D)
    const float scale = ss * f1 * f1 / ((float)Ln * (float)Ln);   // ssq/(L^4 D^2)
    m[b * Dn + d] = s * scale;
}

// ---------------------------------------------------------------------------
// K3 (slim): wave processes 2 rows; m loaded once per wave (L1-hot), ONE
// 6-step butterfly per row, NT stores (out never re-read). x reads are
// L3-resident from K1. grid = (B*L)/8 = 4096 blocks x 256.
// out[b,l,d] = alpha[l] + (x_row . m_b) * x[b,l,d]
// ---------------------------------------------------------------------------
__global__ __launch_bounds__(256)
void k_fused(const float4* __restrict__ x, const float4* __restrict__ m,
             const float* __restrict__ alpha, vfloat4* __restrict__ out) {
    const int wave = threadIdx.x >> 6;
    const int lane = threadIdx.x & 63;
    const int row0 = blockIdx.x * 8 + wave * 2;    // block spans 8 rows, one batch
    const int b    = row0 >> 12;

    const float4* mr = m + (size_t)b * D4;
    float4 m0 = mr[lane], m1 = mr[lane + 64], m2 = mr[lane + 128];

    #pragma unroll
    for (int r = 0; r < 2; ++r) {
        const int row = row0 + r;
        const float4* xr = x + (size_t)row * D4;
        float4 x0 = xr[lane], x1 = xr[lane + 64], x2 = xr[lane + 128];

        float acc = x0.x * m0.x + x0.y * m0.y + x0.z * m0.z + x0.w * m0.w
                  + x1.x * m1.x + x1.y * m1.y + x1.z * m1.z + x1.w * m1.w
                  + x2.x * m2.x + x2.y * m2.y + x2.z * m2.z + x2.w * m2.w;
        #pragma unroll
        for (int off = 1; off < 64; off <<= 1) acc += __shfl_xor(acc, off);

        const float a = alpha[row & (Ln - 1)];
        vfloat4* orow = (vfloat4*)out + (size_t)row * D4;
        vfloat4 o0 = {a + acc * x0.x, a + acc * x0.y, a + acc * x0.z, a + acc * x0.w};
        vfloat4 o1 = {a + acc * x1.x, a + acc * x1.y, a + acc * x1.z, a + acc * x1.w};
        vfloat4 o2 = {a + acc * x2.x, a + acc * x2.y, a + acc * x2.z, a + acc * x2.w};
        __builtin_nontemporal_store(o0, &orow[lane]);
        __builtin_nontemporal_store(o1, &orow[lane + 64]);
        __builtin_nontemporal_store(o2, &orow[lane + 128]);
    }
}

// ---------------------------------------------------------------------------
extern "C" void kernel_launch(void* const* d_in, const int* in_sizes, int n_in,
                              void* d_out, int out_size, void* d_ws, size_t ws_size,
                              hipStream_t stream) {
    const float* x     = (const float*)d_in[0];   // [B, L, D]
    const float* alpha = (const float*)d_in[1];   // [L, 1]
    float* out = (float*)d_out;                   // [B, L, D]

    // ws layout: part[1024*768] (3 MB) | m[8*768] (24 KB)
    float* part = (float*)d_ws;
    float* m    = part + (size_t)CHUNKS_TOT * Dn;

    k_colsum_part<<<CHUNKS_TOT, 192, 0, stream>>>((const float4*)x, (float4*)part);
    k_scale_m<<<Bn, 768, 0, stream>>>(part, m);
    k_fused<<<(Bn * Ln) / 8, 256, 0, stream>>>((const float4*)x, (const float4*)m,
                                               alpha, (vfloat4*)out);
}